// Round 1
// baseline (1852.544 us; speedup 1.0000x reference)
//
#include <hip/hip_runtime.h>
#include <stdint.h>
#include <math.h>

// Problem constants (fixed by the reference)
#define B_ROWS 131072
#define INP 5
#define HID 64
#define NEXP 40
#define OUT_D 5

typedef short bf16x8 __attribute__((ext_vector_type(8)));
typedef float f32x16 __attribute__((ext_vector_type(16)));

__device__ __forceinline__ uint32_t rotl32(uint32_t v, int d) {
  return (v << d) | (v >> (32 - d));
}

// JAX threefry2x32 (20 rounds), matches jax._src.prng lowering exactly.
__device__ __forceinline__ void threefry2x32(uint32_t ks0, uint32_t ks1,
                                             uint32_t x0, uint32_t x1,
                                             uint32_t& o0, uint32_t& o1) {
  uint32_t ks2 = ks0 ^ ks1 ^ 0x1BD11BDAu;
  x0 += ks0; x1 += ks1;
  // i=0: rotations {13,15,26,6}, then x0+=ks1, x1+=ks2+1
  x0 += x1; x1 = rotl32(x1, 13); x1 ^= x0;
  x0 += x1; x1 = rotl32(x1, 15); x1 ^= x0;
  x0 += x1; x1 = rotl32(x1, 26); x1 ^= x0;
  x0 += x1; x1 = rotl32(x1, 6);  x1 ^= x0;
  x0 += ks1; x1 += ks2 + 1u;
  // i=1: {17,29,16,24}, then ks2 / ks0+2
  x0 += x1; x1 = rotl32(x1, 17); x1 ^= x0;
  x0 += x1; x1 = rotl32(x1, 29); x1 ^= x0;
  x0 += x1; x1 = rotl32(x1, 16); x1 ^= x0;
  x0 += x1; x1 = rotl32(x1, 24); x1 ^= x0;
  x0 += ks2; x1 += ks0 + 2u;
  // i=2: {13,15,26,6}, then ks0 / ks1+3
  x0 += x1; x1 = rotl32(x1, 13); x1 ^= x0;
  x0 += x1; x1 = rotl32(x1, 15); x1 ^= x0;
  x0 += x1; x1 = rotl32(x1, 26); x1 ^= x0;
  x0 += x1; x1 = rotl32(x1, 6);  x1 ^= x0;
  x0 += ks0; x1 += ks1 + 3u;
  // i=3: {17,29,16,24}, then ks1 / ks2+4
  x0 += x1; x1 = rotl32(x1, 17); x1 ^= x0;
  x0 += x1; x1 = rotl32(x1, 29); x1 ^= x0;
  x0 += x1; x1 = rotl32(x1, 16); x1 ^= x0;
  x0 += x1; x1 = rotl32(x1, 24); x1 ^= x0;
  x0 += ks1; x1 += ks2 + 4u;
  // i=4: {13,15,26,6}, then ks2 / ks0+5
  x0 += x1; x1 = rotl32(x1, 13); x1 ^= x0;
  x0 += x1; x1 = rotl32(x1, 15); x1 ^= x0;
  x0 += x1; x1 = rotl32(x1, 26); x1 ^= x0;
  x0 += x1; x1 = rotl32(x1, 6);  x1 ^= x0;
  x0 += ks2; x1 += ks0 + 5u;
  o0 = x0; o1 = x1;
}

__device__ __forceinline__ uint16_t f32_to_bf16(float f) {
  uint32_t u = __float_as_uint(f);
  u += 0x7fffu + ((u >> 16) & 1u);  // round-to-nearest-even
  return (uint16_t)(u >> 16);
}

// ---------------------------------------------------------------------------
// Kernel 1: pack triz_w [40][64][64] f32 -> bf16 in MFMA B-operand fragment
// order for v_mfma_f32_32x32x16_bf16:
//   B[k][n]: n = lane&31, k = (lane>>5)*8 + j  (j = element 0..7 in the frag)
// layout: wp[e][kk(4)][nt(2)][lane(64)][j(8)]
// ---------------------------------------------------------------------------
__global__ __launch_bounds__(256) void pack_w_kernel(
    const float* __restrict__ triz_w, uint16_t* __restrict__ wp) {
  int i = blockIdx.x * 256 + threadIdx.x;
  if (i >= NEXP * HID * HID) return;
  int e = i >> 12;         // / 4096
  int rem = i & 4095;
  int k = rem >> 6;        // d index (K dim)
  int f = rem & 63;        // output-feature index (N dim)
  int kk = k >> 4, kl = k & 15;
  int half = kl >> 3, j = kl & 7;
  int nt = f >> 5;
  int lane = half * 32 + (f & 31);
  int dst = ((((e * 4 + kk) * 2 + nt) * 64) + lane) * 8 + j;
  wp[dst] = f32_to_bf16(triz_w[i]);
}

// ---------------------------------------------------------------------------
// Kernel 2: encoder + policy. One wave per 32 rows (4 waves/block).
// Lane j owns feature j of z; fp64 throughout the action-critical path.
// Writes: z as bf16 (ws), probs (f32), actions (f32 into d_out, i32 into ws).
// ---------------------------------------------------------------------------
__global__ __launch_bounds__(256) void enc_policy_kernel(
    const float* __restrict__ x, const float* __restrict__ enc_w,
    const float* __restrict__ enc_b, const float* __restrict__ pol_w,
    const float* __restrict__ pol_b, uint16_t* __restrict__ z_bf16,
    int* __restrict__ actions_i, float* __restrict__ probs_out,
    float* __restrict__ actions_f) {
  const int lane = threadIdx.x & 63;
  const int gw = blockIdx.x * 4 + (threadIdx.x >> 6);
  const int je = lane < NEXP ? lane : NEXP - 1;

  // Row-invariant weights in registers.
  float ew[INP];
#pragma unroll
  for (int d = 0; d < INP; ++d) ew[d] = enc_w[d * HID + lane];
  const double eb = (double)enc_b[lane];
  float pw[HID];
#pragma unroll
  for (int j = 0; j < HID; ++j) pw[j] = pol_w[j * NEXP + je];
  const double pb = (double)pol_b[je];

  const int r0 = gw * 32;
  for (int r = r0; r < r0 + 32; ++r) {
    // z_j = tanh(sum_d x[r,d] * enc_w[d,j] + enc_b[j])  (fp64)
    double a = eb;
#pragma unroll
    for (int d = 0; d < INP; ++d)
      a += (double)x[r * INP + d] * (double)ew[d];
    double z = tanh(a);
    z_bf16[(size_t)r * HID + lane] = f32_to_bf16((float)z);

    // logits[e] = sum_j z_j * pol_w[j,e] + pol_b[e]  via wave broadcast (fp64)
    double l0 = 0.0, l1 = 0.0, l2 = 0.0, l3 = 0.0;
#pragma unroll
    for (int j = 0; j < HID; j += 4) {
      l0 += __shfl(z, j + 0) * (double)pw[j + 0];
      l1 += __shfl(z, j + 1) * (double)pw[j + 1];
      l2 += __shfl(z, j + 2) * (double)pw[j + 2];
      l3 += __shfl(z, j + 3) * (double)pw[j + 3];
    }
    double logit = pb + ((l0 + l1) + (l2 + l3));

    // Gumbel noise, JAX threefry *partitionable* path, key(1) = (0,1):
    //   (o0,o1) = threefry((0,1), (hi=0, lo=flat_idx)); bits = o0 ^ o1
    uint32_t idx = (uint32_t)r * NEXP + (uint32_t)je;
    uint32_t o0, o1;
    threefry2x32(0u, 1u, 0u, idx, o0, o1);
    uint32_t bits = o0 ^ o1;
    const float TINY = 1.17549435e-38f;
    float uf = __uint_as_float((bits >> 9) | 0x3f800000u) - 1.0f;
    uf = uf * (1.0f - TINY) + TINY;
    uf = fmaxf(uf, TINY);
    double g = -log(-log((double)uf));
    double val = logit + g;

    // argmax with first-occurrence tie-break (jnp.argmax semantics)
    double mv = (lane < NEXP) ? val : -1.0e300;
    int mi = (lane < NEXP) ? lane : 64;
#pragma unroll
    for (int off = 32; off > 0; off >>= 1) {
      double ov = __shfl_down(mv, off);
      int oi = __shfl_down(mi, off);
      if (ov > mv || (ov == mv && oi < mi)) { mv = ov; mi = oi; }
    }
    mi = __shfl(mi, 0);
    if (lane == 0) {
      actions_i[r] = mi;
      actions_f[r] = (float)mi;
    }

    // softmax probs (fp64 math, f32 store; threshold is 0.78 absolute)
    double lm = (lane < NEXP) ? logit : -1.0e300;
#pragma unroll
    for (int off = 32; off > 0; off >>= 1) {
      double ov = __shfl_down(lm, off);
      lm = ov > lm ? ov : lm;
    }
    lm = __shfl(lm, 0);
    double p = (lane < NEXP) ? exp(logit - lm) : 0.0;
    double s = p;
#pragma unroll
    for (int off = 32; off > 0; off >>= 1) s += __shfl_down(s, off);
    s = __shfl(s, 0);
    if (lane < NEXP) probs_out[(size_t)r * NEXP + lane] = (float)(p / s);
  }
}

// ---------------------------------------------------------------------------
// Kernel 3: h[b,e,f] = relu(z[b,:] @ triz_w[e,:,:] + triz_b[e,:])
// bf16 MFMA 32x32x16. Wave owns 32 rows; A-fragments (z) loaded once into
// registers and reused across all 40 experts (z is expert-invariant).
// Write-BW-bound: 1.34 GB of h stores.
// ---------------------------------------------------------------------------
__global__ __launch_bounds__(256) void triz_kernel(
    const uint16_t* __restrict__ z_bf16, const uint16_t* __restrict__ wp,
    const float* __restrict__ triz_b, float* __restrict__ h) {
  const int lane = threadIdx.x & 63;
  const int wv = threadIdx.x >> 6;
  const int m0 = blockIdx.x * 128 + wv * 32;
  const int half = lane >> 5;
  const int col = lane & 31;  // also the A-fragment row (lane&31)

  // A-fragment: A[m=lane&31][k = half*8 + j], k-chunk kk adds kk*16.
  const uint16_t* zr = z_bf16 + (size_t)(m0 + col) * HID + half * 8;
  bf16x8 A[4];
#pragma unroll
  for (int kk = 0; kk < 4; ++kk)
    A[kk] = *reinterpret_cast<const bf16x8*>(zr + kk * 16);

  // Per-lane store base: row offset 4*half folded in; col folded in.
  float* hb = h + (size_t)(m0 + (half << 2)) * (NEXP * HID) + col;

  const bf16x8* wpv = reinterpret_cast<const bf16x8*>(wp);
  for (int e = 0; e < NEXP; ++e) {
    const bf16x8* wpe = wpv + (size_t)e * 512 + lane;
    f32x16 acc0 = {}, acc1 = {};
#pragma unroll
    for (int kk = 0; kk < 4; ++kk) {
      bf16x8 b0 = wpe[(kk * 2 + 0) * 64];
      bf16x8 b1 = wpe[(kk * 2 + 1) * 64];
      acc0 = __builtin_amdgcn_mfma_f32_32x32x16_bf16(A[kk], b0, acc0, 0, 0, 0);
      acc1 = __builtin_amdgcn_mfma_f32_32x32x16_bf16(A[kk], b1, acc1, 0, 0, 0);
    }
    float bv0 = triz_b[e * HID + col];
    float bv1 = triz_b[e * HID + 32 + col];
#pragma unroll
    for (int reg = 0; reg < 16; ++reg) {
      int row = (reg & 3) + ((reg >> 2) << 3);  // + 4*half already in hb
      size_t off = (size_t)row * (NEXP * HID) + (size_t)e * HID;
      hb[off] = fmaxf(acc0[reg] + bv0, 0.0f);
      hb[off + 32] = fmaxf(acc1[reg] + bv1, 0.0f);
    }
  }
}

// ---------------------------------------------------------------------------
// Kernel 4: out[b,:] = h[b, action[b], :] @ dec_w + dec_b
// ---------------------------------------------------------------------------
__global__ __launch_bounds__(256) void decode_kernel(
    const float* __restrict__ h, const int* __restrict__ actions_i,
    const float* __restrict__ dec_w, const float* __restrict__ dec_b,
    float* __restrict__ out) {
  int b = blockIdx.x * 256 + threadIdx.x;
  if (b >= B_ROWS) return;
  int a = actions_i[b];
  const float4* hr =
      reinterpret_cast<const float4*>(h + ((size_t)b * NEXP + a) * HID);
  float acc0 = dec_b[0], acc1 = dec_b[1], acc2 = dec_b[2], acc3 = dec_b[3],
        acc4 = dec_b[4];
#pragma unroll
  for (int q = 0; q < 16; ++q) {
    float4 hv = hr[q];
#pragma unroll
    for (int t = 0; t < 4; ++t) {
      float v = (&hv.x)[t];
      int f = q * 4 + t;
      acc0 += v * dec_w[f * 5 + 0];
      acc1 += v * dec_w[f * 5 + 1];
      acc2 += v * dec_w[f * 5 + 2];
      acc3 += v * dec_w[f * 5 + 3];
      acc4 += v * dec_w[f * 5 + 4];
    }
  }
  float* o = out + (size_t)b * OUT_D;
  o[0] = acc0; o[1] = acc1; o[2] = acc2; o[3] = acc3; o[4] = acc4;
}

extern "C" void kernel_launch(void* const* d_in, const int* in_sizes, int n_in,
                              void* d_out, int out_size, void* d_ws,
                              size_t ws_size, hipStream_t stream) {
  const float* x = (const float*)d_in[0];
  const float* enc_w = (const float*)d_in[1];
  const float* enc_b = (const float*)d_in[2];
  const float* triz_w = (const float*)d_in[3];
  const float* triz_b = (const float*)d_in[4];
  const float* pol_w = (const float*)d_in[5];
  const float* pol_b = (const float*)d_in[6];
  const float* dec_w = (const float*)d_in[7];
  const float* dec_b = (const float*)d_in[8];

  // d_out: [B,5] out | [B,40] probs | [B] actions | [B,40,64] h  (all f32)
  float* out = (float*)d_out;
  float* probs = out + (size_t)B_ROWS * OUT_D;
  float* actions_f = probs + (size_t)B_ROWS * NEXP;
  float* h = actions_f + B_ROWS;

  // ws: z_bf16 (16 MiB) | wpack (320 KiB) | actions_i (512 KiB)
  uint8_t* ws = (uint8_t*)d_ws;
  uint16_t* z_bf16 = (uint16_t*)ws;
  uint16_t* wpack = (uint16_t*)(ws + (size_t)B_ROWS * HID * 2);
  int* actions_i =
      (int*)(ws + (size_t)B_ROWS * HID * 2 + (size_t)NEXP * HID * HID * 2);

  pack_w_kernel<<<(NEXP * HID * HID + 255) / 256, 256, 0, stream>>>(triz_w,
                                                                    wpack);
  enc_policy_kernel<<<B_ROWS / 128, 256, 0, stream>>>(
      x, enc_w, enc_b, pol_w, pol_b, z_bf16, actions_i, probs, actions_f);
  triz_kernel<<<B_ROWS / 128, 256, 0, stream>>>(z_bf16, wpack, triz_b, h);
  decode_kernel<<<B_ROWS / 256, 256, 0, stream>>>(h, actions_i, dec_w, dec_b,
                                                  out);
}